// Round 11
// baseline (40.393 us; speedup 1.0000x reference)
//
#include <hip/hip_runtime.h>

// Problem constants (from reference)
#define N_ATOMS   500000
#define N_ALT     4
#define NB        2      // N_BATCH
#define NC        4      // N_CHAIN
#define NR        50000  // N_RES
#define SG_HASH   16
#define TEMP      298.0f

// Output layout (flat float32):
//   [0, 1600000)            residueEnergy (2,4,50000,4)
//   [1600000, 3600000)      atomEnergy    (500000,4)
//   [3600000, 3600000+P)    sulfur        (P,) as 0.0/1.0
#define RESE_SIZE  (NB * NC * NR * N_ALT)   // 1,600,000
#define ATOME_SIZE (N_ATOMS * N_ALT)        // 2,000,000
#define ZERO_F4    ((RESE_SIZE + ATOME_SIZE) / 4)   // 900,000 float4 stores

#define MASK_W64   ((N_ATOMS + 63) / 64)    // 7813 u64 = 62,504 B
#define MASK_W32   (MASK_W64 * 2)           // 15626 u32
#define MASK_V4    ((MASK_W32 + 3) / 4)     // 3907 uint4

#define PPT 16                               // pairs per thread, single sweep

// Native clang vector type — __builtin_nontemporal_store rejects the
// HIP_vector_type struct float4.
typedef float fltx4 __attribute__((ext_vector_type(4)));

// ---------------------------------------------------------------------------
// Kernel A (prep): zero resE+atomE with float4 stores AND build the packed
// SG bitmask via __ballot — one launch.
// ---------------------------------------------------------------------------
__global__ __launch_bounds__(1024) void prep_kernel(
    const int* __restrict__ adesc,              // (N,4)
    float* __restrict__ zero_base,              // resE (zero 3.6M floats)
    unsigned long long* __restrict__ mask)      // (MASK_W64,)
{
    int i = blockIdx.x * 1024 + threadIdx.x;

    if (i < ZERO_F4)
        reinterpret_cast<float4*>(zero_base)[i] = make_float4(0.f, 0.f, 0.f, 0.f);

    bool s = false;
    if (i < N_ATOMS) s = (adesc[(size_t)i * 4 + 3] == SG_HASH);
    unsigned long long b = __ballot(s);
    if (i < N_ATOMS && (threadIdx.x & 63) == 0) mask[i >> 6] = b;
}

// ---------------------------------------------------------------------------
// Cold path: full energy + scatter for a sulfur pair (~0.1% of pairs).
// ---------------------------------------------------------------------------
__device__ __forceinline__ void heavy_pair(
    int p0, int p1,
    const float* __restrict__ coords,
    const int*   __restrict__ adesc,
    const int*   __restrict__ altmask,
    float* __restrict__ resE,
    float* __restrict__ atomE)
{
    int4 d0 = *reinterpret_cast<const int4*>(adesc + (size_t)p0 * 4);
    int4 d1 = *reinterpret_cast<const int4*>(adesc + (size_t)p1 * 4);

    float dx = coords[(size_t)p0 * 3 + 0] - coords[(size_t)p1 * 3 + 0] + 1e-6f;
    float dy = coords[(size_t)p0 * 3 + 1] - coords[(size_t)p1 * 3 + 1] + 1e-6f;
    float dz = coords[(size_t)p0 * 3 + 2] - coords[(size_t)p1 * 3 + 2] + 1e-6f;
    float dist = sqrtf(dx * dx + dy * dy + dz * dz);

    float rd = fabsf((float)(d0.z - d1.z));      // sulfur => rd >= 1, log safe
    float energy = -0.001f * TEMP * (2.1f + 2.9823825f * logf(rd))
                 + 5.0f * fabsf(dist - 2.04f);
    float netE = 0.5f * energy;

    int4 m0 = *reinterpret_cast<const int4*>(altmask + (size_t)p0 * 4);
    int4 m1 = *reinterpret_cast<const int4*>(altmask + (size_t)p1 * 4);

    int f0 = ((d0.x * NC + d0.y) * NR + d0.z) * N_ALT;
    int f1 = ((d1.x * NC + d1.y) * NR + d1.z) * N_ALT;

    const int* m0p = &m0.x;
    const int* m1p = &m1.x;
#pragma unroll
    for (int a = 0; a < N_ALT; ++a) {
        if (m0p[a] & m1p[a]) {
            atomicAdd(atomE + (size_t)p0 * N_ALT + a, netE);
            atomicAdd(atomE + (size_t)p1 * N_ALT + a, netE);
            atomicAdd(resE + f0 + a, netE);
            atomicAdd(resE + f1 + a, netE);
        }
    }
}

__device__ __forceinline__ bool probe2(const unsigned int* __restrict__ lm,
                                       int a, int b) {
    unsigned m = (lm[a >> 5] >> (a & 31)) & (lm[b >> 5] >> (b & 31));
    return m & 1u;
}

// ---------------------------------------------------------------------------
// Kernel B (single sweep, 16 pairs/thread):
//   broadcast 62.5 KB bitmask into LDS -> __syncthreads -> 8 independent
//   int4 pair loads (128 B/lane in flight, issued together, strictly AFTER
//   the barrier — r7 showed loads-before-barrier force a block-wide
//   vmcnt(0) drain at s_barrier) -> 32 LDS probes -> 4 NT float4 sulfur
//   stores (NT keeps the touch-once write stream out of L2/L3 so the pair
//   stream stays resident, r10 evidence) -> rare heavy path.
// 489 blocks x 1024 threads, 62.5 KB LDS -> 2 blocks/CU, all resident.
// ---------------------------------------------------------------------------
__global__ __launch_bounds__(1024) void disulfide_pair_kernel(
    const float* __restrict__ coords,
    const int*   __restrict__ adesc,    // (N,4)
    const int*   __restrict__ pairs,    // (P,2)
    const int*   __restrict__ altmask,  // (N,4) 0/1
    const unsigned int* __restrict__ sgmask32,
    float* __restrict__ resE,
    float* __restrict__ atomE,
    float* __restrict__ sulfur,
    int P)
{
    __shared__ unsigned int lmask[MASK_V4 * 4];   // 62,512 B

    {
        const uint4* g4 = reinterpret_cast<const uint4*>(sgmask32);
        uint4* l4 = reinterpret_cast<uint4*>(lmask);
#pragma unroll
        for (int k = 0; k < 4; ++k) {
            int w = threadIdx.x + k * 1024;
            if (w < MASK_V4) l4[w] = g4[w];
        }
    }
    __syncthreads();

    const int tid = blockIdx.x * 1024 + threadIdx.x;
    const int i0  = tid * PPT;
    if (i0 >= P) return;    // P % 16 == 0: full batch in-bounds when active

    // 8 independent 16B loads — all issued together, after the barrier.
    const int4* pp = reinterpret_cast<const int4*>(pairs + (size_t)i0 * 2);
    int4 v0 = pp[0], v1 = pp[1], v2 = pp[2], v3 = pp[3];
    int4 v4 = pp[4], v5 = pp[5], v6 = pp[6], v7 = pp[7];

    bool s0  = probe2(lmask, v0.x, v0.y), s1  = probe2(lmask, v0.z, v0.w);
    bool s2  = probe2(lmask, v1.x, v1.y), s3  = probe2(lmask, v1.z, v1.w);
    bool s4  = probe2(lmask, v2.x, v2.y), s5  = probe2(lmask, v2.z, v2.w);
    bool s6  = probe2(lmask, v3.x, v3.y), s7  = probe2(lmask, v3.z, v3.w);
    bool s8  = probe2(lmask, v4.x, v4.y), s9  = probe2(lmask, v4.z, v4.w);
    bool s10 = probe2(lmask, v5.x, v5.y), s11 = probe2(lmask, v5.z, v5.w);
    bool s12 = probe2(lmask, v6.x, v6.y), s13 = probe2(lmask, v6.z, v6.w);
    bool s14 = probe2(lmask, v7.x, v7.y), s15 = probe2(lmask, v7.z, v7.w);

    fltx4* sp = reinterpret_cast<fltx4*>(sulfur + i0);
    fltx4 w0 = {s0  ? 1.f : 0.f, s1  ? 1.f : 0.f, s2  ? 1.f : 0.f, s3  ? 1.f : 0.f};
    fltx4 w1 = {s4  ? 1.f : 0.f, s5  ? 1.f : 0.f, s6  ? 1.f : 0.f, s7  ? 1.f : 0.f};
    fltx4 w2 = {s8  ? 1.f : 0.f, s9  ? 1.f : 0.f, s10 ? 1.f : 0.f, s11 ? 1.f : 0.f};
    fltx4 w3 = {s12 ? 1.f : 0.f, s13 ? 1.f : 0.f, s14 ? 1.f : 0.f, s15 ? 1.f : 0.f};
    __builtin_nontemporal_store(w0, sp + 0);
    __builtin_nontemporal_store(w1, sp + 1);
    __builtin_nontemporal_store(w2, sp + 2);
    __builtin_nontemporal_store(w3, sp + 3);

    if (s0)  heavy_pair(v0.x, v0.y, coords, adesc, altmask, resE, atomE);
    if (s1)  heavy_pair(v0.z, v0.w, coords, adesc, altmask, resE, atomE);
    if (s2)  heavy_pair(v1.x, v1.y, coords, adesc, altmask, resE, atomE);
    if (s3)  heavy_pair(v1.z, v1.w, coords, adesc, altmask, resE, atomE);
    if (s4)  heavy_pair(v2.x, v2.y, coords, adesc, altmask, resE, atomE);
    if (s5)  heavy_pair(v2.z, v2.w, coords, adesc, altmask, resE, atomE);
    if (s6)  heavy_pair(v3.x, v3.y, coords, adesc, altmask, resE, atomE);
    if (s7)  heavy_pair(v3.z, v3.w, coords, adesc, altmask, resE, atomE);
    if (s8)  heavy_pair(v4.x, v4.y, coords, adesc, altmask, resE, atomE);
    if (s9)  heavy_pair(v4.z, v4.w, coords, adesc, altmask, resE, atomE);
    if (s10) heavy_pair(v5.x, v5.y, coords, adesc, altmask, resE, atomE);
    if (s11) heavy_pair(v5.z, v5.w, coords, adesc, altmask, resE, atomE);
    if (s12) heavy_pair(v6.x, v6.y, coords, adesc, altmask, resE, atomE);
    if (s13) heavy_pair(v6.z, v6.w, coords, adesc, altmask, resE, atomE);
    if (s14) heavy_pair(v7.x, v7.y, coords, adesc, altmask, resE, atomE);
    if (s15) heavy_pair(v7.z, v7.w, coords, adesc, altmask, resE, atomE);
}

extern "C" void kernel_launch(void* const* d_in, const int* in_sizes, int n_in,
                              void* d_out, int out_size, void* d_ws, size_t ws_size,
                              hipStream_t stream) {
    const float* coords  = (const float*)d_in[0];
    const int*   adesc   = (const int*)d_in[1];
    // d_in[2] = atom_number (unused)
    const int*   pairs   = (const int*)d_in[3];
    const int*   altmask = (const int*)d_in[4];
    // d_in[5] = partners (unused), d_in[6] = facc (unused)

    const int P = in_sizes[3] / 2;   // 8,000,000

    float* out    = (float*)d_out;
    float* resE   = out;
    float* atomE  = out + RESE_SIZE;
    float* sulfur = out + RESE_SIZE + ATOME_SIZE;

    unsigned long long* sgmask = (unsigned long long*)d_ws;   // 62.5 KB

    // Kernel A: zero accumulated outputs + build SG bitmask (one launch).
    {
        const int threads = 1024;
        const int blocks  = (ZERO_F4 + threads - 1) / threads;   // 879
        prep_kernel<<<blocks, threads, 0, stream>>>(adesc, resE, sgmask);
    }

    // Kernel B: single-sweep pair streaming with LDS-resident bitmask.
    {
        const int threads = 1024;
        const int work    = (P + PPT - 1) / PPT;                 // 500,000
        const int blocks  = (work + threads - 1) / threads;      // 489
        disulfide_pair_kernel<<<blocks, threads, 0, stream>>>(
            coords, adesc, pairs, altmask, (const unsigned int*)sgmask,
            resE, atomE, sulfur, P);
    }
}

// Round 12
// 28.736 us; speedup vs baseline: 1.4057x; 1.4057x over previous
//
#include <hip/hip_runtime.h>

// Problem constants (from reference)
#define N_ATOMS   500000
#define N_ALT     4
#define NB        2      // N_BATCH
#define NC        4      // N_CHAIN
#define NR        50000  // N_RES
#define SG_HASH   16
#define TEMP      298.0f

// Output layout (flat float32):
//   [0, 1600000)            residueEnergy (2,4,50000,4)
//   [1600000, 3600000)      atomEnergy    (500000,4)
//   [3600000, 3600000+P)    sulfur        (P,) as 0.0/1.0
#define RESE_SIZE  (NB * NC * NR * N_ALT)   // 1,600,000
#define ATOME_SIZE (N_ATOMS * N_ALT)        // 2,000,000
#define ZERO_F4    ((RESE_SIZE + ATOME_SIZE) / 4)   // 900,000 float4 stores

#define MASK_W64   ((N_ATOMS + 63) / 64)    // 7813 u64 = 62,504 B
#define MASK_W32   (MASK_W64 * 2)           // 15626 u32
#define MASK_V4    ((MASK_W32 + 3) / 4)     // 3907 uint4

// Native clang vector type — __builtin_nontemporal_store rejects the
// HIP_vector_type struct float4.
typedef float fltx4 __attribute__((ext_vector_type(4)));

// ---------------------------------------------------------------------------
// Kernel A (prep): zero resE+atomE with float4 stores AND build the packed
// SG bitmask via __ballot — one launch.
// ---------------------------------------------------------------------------
__global__ __launch_bounds__(1024) void prep_kernel(
    const int* __restrict__ adesc,              // (N,4)
    float* __restrict__ zero_base,              // resE (zero 3.6M floats)
    unsigned long long* __restrict__ mask)      // (MASK_W64,)
{
    int i = blockIdx.x * 1024 + threadIdx.x;

    if (i < ZERO_F4)
        reinterpret_cast<float4*>(zero_base)[i] = make_float4(0.f, 0.f, 0.f, 0.f);

    bool s = false;
    if (i < N_ATOMS) s = (adesc[(size_t)i * 4 + 3] == SG_HASH);
    unsigned long long b = __ballot(s);
    if (i < N_ATOMS && (threadIdx.x & 63) == 0) mask[i >> 6] = b;
}

// ---------------------------------------------------------------------------
// Cold path: full energy + scatter for a sulfur pair (~0.1% of pairs).
// ---------------------------------------------------------------------------
__device__ __forceinline__ void heavy_pair(
    int p0, int p1,
    const float* __restrict__ coords,
    const int*   __restrict__ adesc,
    const int*   __restrict__ altmask,
    float* __restrict__ resE,
    float* __restrict__ atomE)
{
    int4 d0 = *reinterpret_cast<const int4*>(adesc + (size_t)p0 * 4);
    int4 d1 = *reinterpret_cast<const int4*>(adesc + (size_t)p1 * 4);

    float dx = coords[(size_t)p0 * 3 + 0] - coords[(size_t)p1 * 3 + 0] + 1e-6f;
    float dy = coords[(size_t)p0 * 3 + 1] - coords[(size_t)p1 * 3 + 1] + 1e-6f;
    float dz = coords[(size_t)p0 * 3 + 2] - coords[(size_t)p1 * 3 + 2] + 1e-6f;
    float dist = sqrtf(dx * dx + dy * dy + dz * dz);

    float rd = fabsf((float)(d0.z - d1.z));      // sulfur => rd >= 1, log safe
    float energy = -0.001f * TEMP * (2.1f + 2.9823825f * logf(rd))
                 + 5.0f * fabsf(dist - 2.04f);
    float netE = 0.5f * energy;

    int4 m0 = *reinterpret_cast<const int4*>(altmask + (size_t)p0 * 4);
    int4 m1 = *reinterpret_cast<const int4*>(altmask + (size_t)p1 * 4);

    int f0 = ((d0.x * NC + d0.y) * NR + d0.z) * N_ALT;
    int f1 = ((d1.x * NC + d1.y) * NR + d1.z) * N_ALT;

    const int* m0p = &m0.x;
    const int* m1p = &m1.x;
#pragma unroll
    for (int a = 0; a < N_ALT; ++a) {
        if (m0p[a] & m1p[a]) {
            atomicAdd(atomE + (size_t)p0 * N_ALT + a, netE);
            atomicAdd(atomE + (size_t)p1 * N_ALT + a, netE);
            atomicAdd(resE + f0 + a, netE);
            atomicAdd(resE + f1 + a, netE);
        }
    }
}

__device__ __forceinline__ bool probe2(const unsigned int* __restrict__ lm,
                                       int a, int b) {
    unsigned m = (lm[a >> 5] >> (a & 31)) & (lm[b >> 5] >> (b & 31));
    return m & 1u;
}

// ---------------------------------------------------------------------------
// Kernel B (round-10 structure, best measured at 28.8 us): broadcast the
// 62.5 KB SG bitmask into LDS, sync, then grid-stride loop with 8 pairs
// per thread per iteration (512 blocks -> 2 iterations/thread).
//   - plain cached LOADS (NT loads regressed, r5; L3 keeps the pair
//     stream half-resident across replays, r2 FETCH evidence)
//   - NT STORES on sulfur only (touch-once write stream bypasses caches
//     so reads stay resident; r10: -0.6 us)
//   - loads strictly AFTER the barrier (r7: loads-before-barrier force a
//     block-wide vmcnt(0) drain at s_barrier, -8 us)
//   - no explicit prefetch/pipeline (r8: neutral; compiler + 32 waves/CU
//     TLP already cover it), no one-shot structure (r11: -11.6 us),
//     no cooperative fusion (r9: -36 us).
// 1024-thread blocks, 62.5 KB LDS -> 2 blocks/CU = 32 waves/CU.
// ---------------------------------------------------------------------------
__global__ __launch_bounds__(1024) void disulfide_pair_kernel(
    const float* __restrict__ coords,
    const int*   __restrict__ adesc,    // (N,4)
    const int*   __restrict__ pairs,    // (P,2)
    const int*   __restrict__ altmask,  // (N,4) 0/1
    const unsigned int* __restrict__ sgmask32,
    float* __restrict__ resE,
    float* __restrict__ atomE,
    float* __restrict__ sulfur,
    int P)
{
    __shared__ unsigned int lmask[MASK_V4 * 4];   // 62,512 B

    {
        const uint4* g4 = reinterpret_cast<const uint4*>(sgmask32);
        uint4* l4 = reinterpret_cast<uint4*>(lmask);
#pragma unroll
        for (int k = 0; k < 4; ++k) {
            int w = threadIdx.x + k * 1024;
            if (w < MASK_V4) l4[w] = g4[w];
        }
    }
    __syncthreads();

    const int tid    = blockIdx.x * 1024 + threadIdx.x;
    const int stride = gridDim.x * 1024 * 8;

    for (int i0 = tid * 8; i0 < P; i0 += stride) {
        const int4* pp = reinterpret_cast<const int4*>(pairs + (size_t)i0 * 2);
        int4 pa = pp[0];   // pairs i0,   i0+1
        int4 pb = pp[1];   // pairs i0+2, i0+3
        int4 pc = pp[2];   // pairs i0+4, i0+5
        int4 pd = pp[3];   // pairs i0+6, i0+7

        bool s0 = probe2(lmask, pa.x, pa.y);
        bool s1 = probe2(lmask, pa.z, pa.w);
        bool s2 = probe2(lmask, pb.x, pb.y);
        bool s3 = probe2(lmask, pb.z, pb.w);
        bool s4 = probe2(lmask, pc.x, pc.y);
        bool s5 = probe2(lmask, pc.z, pc.w);
        bool s6 = probe2(lmask, pd.x, pd.y);
        bool s7 = probe2(lmask, pd.z, pd.w);

        fltx4 sv0 = {s0 ? 1.0f : 0.0f, s1 ? 1.0f : 0.0f,
                     s2 ? 1.0f : 0.0f, s3 ? 1.0f : 0.0f};
        fltx4 sv1 = {s4 ? 1.0f : 0.0f, s5 ? 1.0f : 0.0f,
                     s6 ? 1.0f : 0.0f, s7 ? 1.0f : 0.0f};
        fltx4* sp = reinterpret_cast<fltx4*>(sulfur + i0);
        __builtin_nontemporal_store(sv0, sp + 0);
        __builtin_nontemporal_store(sv1, sp + 1);

        if (s0) heavy_pair(pa.x, pa.y, coords, adesc, altmask, resE, atomE);
        if (s1) heavy_pair(pa.z, pa.w, coords, adesc, altmask, resE, atomE);
        if (s2) heavy_pair(pb.x, pb.y, coords, adesc, altmask, resE, atomE);
        if (s3) heavy_pair(pb.z, pb.w, coords, adesc, altmask, resE, atomE);
        if (s4) heavy_pair(pc.x, pc.y, coords, adesc, altmask, resE, atomE);
        if (s5) heavy_pair(pc.z, pc.w, coords, adesc, altmask, resE, atomE);
        if (s6) heavy_pair(pd.x, pd.y, coords, adesc, altmask, resE, atomE);
        if (s7) heavy_pair(pd.z, pd.w, coords, adesc, altmask, resE, atomE);
    }
}

extern "C" void kernel_launch(void* const* d_in, const int* in_sizes, int n_in,
                              void* d_out, int out_size, void* d_ws, size_t ws_size,
                              hipStream_t stream) {
    const float* coords  = (const float*)d_in[0];
    const int*   adesc   = (const int*)d_in[1];
    // d_in[2] = atom_number (unused)
    const int*   pairs   = (const int*)d_in[3];
    const int*   altmask = (const int*)d_in[4];
    // d_in[5] = partners (unused), d_in[6] = facc (unused)

    const int P = in_sizes[3] / 2;   // 8,000,000

    float* out    = (float*)d_out;
    float* resE   = out;
    float* atomE  = out + RESE_SIZE;
    float* sulfur = out + RESE_SIZE + ATOME_SIZE;

    unsigned long long* sgmask = (unsigned long long*)d_ws;   // 62.5 KB

    // Kernel A: zero accumulated outputs + build SG bitmask (one launch).
    {
        const int threads = 1024;
        const int blocks  = (ZERO_F4 + threads - 1) / threads;   // 879
        prep_kernel<<<blocks, threads, 0, stream>>>(adesc, resE, sgmask);
    }

    // Kernel B: pair streaming with LDS-resident bitmask.
    {
        const int threads = 1024;
        const int blocks  = 512;     // 2 resident blocks/CU on 256 CUs
        disulfide_pair_kernel<<<blocks, threads, 0, stream>>>(
            coords, adesc, pairs, altmask, (const unsigned int*)sgmask,
            resE, atomE, sulfur, P);
    }
}